// Round 1
// baseline (331.804 us; speedup 1.0000x reference)
//
#include <hip/hip_runtime.h>

#define Hh 128
#define Ww 256
#define Cc 64
#define COUT 64
#define Bb 4
#define HW (Hh*Ww)

// Pre-transpose weight (Cout, C, 3, 3) -> wt[k][c][o] so the hot loop's
// weight reads are lane-uniform and contiguous in o (scalar-load friendly).
__global__ void wtrans(const float* __restrict__ wsrc, float* __restrict__ wdst) {
    int i = blockIdx.x * 256 + threadIdx.x;
    if (i >= COUT * Cc * 9) return;
    int k = i % 9;
    int c = (i / 9) % Cc;
    int o = i / (9 * Cc);
    wdst[(k * Cc + c) * COUT + o] = wsrc[i];
}

__launch_bounds__(256, 2)
__global__ void dcn_kernel(const float* __restrict__ x,
                           const float* __restrict__ offset,
                           const float* __restrict__ wt,
                           const float* __restrict__ bias,
                           float* __restrict__ out) {
    const int tid = threadIdx.x;
    const int w = blockIdx.x * 64 + (tid & 63);   // lanes along w: coalesced
    const int h = blockIdx.y * 4 + (tid >> 6);
    const int b = blockIdx.z;

    float acc[COUT];
#pragma unroll
    for (int o = 0; o < COUT; ++o) acc[o] = 0.f;

    const float* xb = x + b * Cc * HW;
    const float* offb = offset + b * 18 * HW;
    const int pix = h * Ww + w;

    for (int ki = 0; ki < 3; ++ki) {
        for (int kj = 0; kj < 3; ++kj) {
            const int k = ki * 3 + kj;
            const float dy = offb[(2 * k) * HW + pix];
            const float dx = offb[(2 * k + 1) * HW + pix];
            const float py = (float)(h - 1 + ki) + dy;
            const float px = (float)(w - 1 + kj) + dx;
            const float y0f = floorf(py), x0f = floorf(px);
            const int y0 = (int)y0f, x0 = (int)x0f;
            const float ly = py - y0f, lx = px - x0f;
            const int y1 = y0 + 1, x1 = x0 + 1;
            const bool vy0 = ((unsigned)y0 < Hh), vy1 = ((unsigned)y1 < Hh);
            const bool vx0 = ((unsigned)x0 < Ww), vx1 = ((unsigned)x1 < Ww);
            float w00 = (1.f - ly) * (1.f - lx); if (!(vy0 && vx0)) w00 = 0.f;
            float w01 = (1.f - ly) * lx;         if (!(vy0 && vx1)) w01 = 0.f;
            float w10 = ly * (1.f - lx);         if (!(vy1 && vx0)) w10 = 0.f;
            float w11 = ly * lx;                 if (!(vy1 && vx1)) w11 = 0.f;
            const int y0c = min(max(y0, 0), Hh - 1), y1c = min(max(y1, 0), Hh - 1);
            const int x0c = min(max(x0, 0), Ww - 1), x1c = min(max(x1, 0), Ww - 1);
            const int a00 = y0c * Ww + x0c, a01 = y0c * Ww + x1c;
            const int a10 = y1c * Ww + x0c, a11 = y1c * Ww + x1c;

            const float* wk = wt + k * Cc * COUT;
            const float* xc = xb;
            for (int c = 0; c < Cc; ++c, xc += HW) {
                const float v = w00 * xc[a00] + w01 * xc[a01]
                              + w10 * xc[a10] + w11 * xc[a11];
                const float* wp = wk + c * COUT;   // lane-uniform -> s_load
#pragma unroll
                for (int o = 0; o < COUT; ++o)
                    acc[o] = fmaf(v, wp[o], acc[o]);
            }
        }
    }

    float* op = out + b * COUT * HW + pix;
#pragma unroll
    for (int o = 0; o < COUT; ++o)
        op[o * HW] = acc[o] + bias[o];   // bias: lane-uniform scalar load
}

extern "C" void kernel_launch(void* const* d_in, const int* in_sizes, int n_in,
                              void* d_out, int out_size, void* d_ws, size_t ws_size,
                              hipStream_t stream) {
    const float* x      = (const float*)d_in[0];
    const float* offset = (const float*)d_in[1];
    const float* weight = (const float*)d_in[2];
    const float* bias   = (const float*)d_in[3];
    float* out = (float*)d_out;
    float* wt  = (float*)d_ws;   // 9*64*64 floats = 144 KiB scratch

    wtrans<<<dim3((COUT * Cc * 9 + 255) / 256), 256, 0, stream>>>(weight, wt);
    dcn_kernel<<<dim3(Ww / 64, Hh / 4, Bb), 256, 0, stream>>>(x, offset, wt, bias, out);
}